// Round 6
// baseline (273.286 us; speedup 1.0000x reference)
//
#include <hip/hip_runtime.h>
#include <math.h>

constexpr int NFFT = 524288;   // 2^19 >= T + L - 1 = 485099
constexpr int N1   = 512;      // column FFT length (strided dim)
constexpr int N2   = 1024;     // row FFT length (contiguous dim)
constexpr int TT   = 441000;   // multiple of 4
constexpr int IRL  = 44100;    // multiple of 4
constexpr int NSIG = 16;       // 32 real batches packed as 16 complex signals
constexpr int C1   = 16;       // columns per block in stage1/3
constexpr int R2   = 4;        // rows per block in stage2
constexpr int GRID = 512;      // persistent grid: 2 blocks/CU x 256 CU

// -2*pi/NFFT
constexpr float ANG0   = -1.1984224905891939e-5f;
constexpr float NTWOPI = -6.2831853071795864769f;

__device__ inline float2 cmulf(float2 a, float2 b) {
    return make_float2(a.x * b.x - a.y * b.y, a.x * b.y + a.y * b.x);
}
__device__ inline float2 cadd(float2 a, float2 b) { return make_float2(a.x + b.x, a.y + b.y); }
__device__ inline float2 csub(float2 a, float2 b) { return make_float2(a.x - b.x, a.y - b.y); }

// Radix-4 Stockham butterfly (validated rounds 3-5). Outputs to q+4sp+{0,s,2s,3s},
// twiddles W^{ps},W^{2ps},W^{3ps}; cross term -i fwd / +i inv (caller conjugates w).
template<bool INV>
__device__ inline void bfly4(const float2* u, float2 w1, float2 w2, float2 w3, float2* o) {
    float2 t0 = cadd(u[0], u[2]);
    float2 t1 = csub(u[0], u[2]);
    float2 t2 = cadd(u[1], u[3]);
    float2 t3 = csub(u[1], u[3]);
    float2 r3 = INV ? make_float2(-t3.y, t3.x) : make_float2(t3.y, -t3.x);
    o[0] = cadd(t0, t2);
    o[1] = cmulf(cadd(t1, r3), w1);
    o[2] = cmulf(csub(t0, t2), w2);
    o[3] = cmulf(csub(t1, r3), w3);
}
// Unit-twiddle variant (s = L/4 final pass: p=0 -> w=1).
template<bool INV>
__device__ inline void bfly4_nw(const float2* u, float2* o) {
    float2 t0 = cadd(u[0], u[2]);
    float2 t1 = csub(u[0], u[2]);
    float2 t2 = cadd(u[1], u[3]);
    float2 t3 = csub(u[1], u[3]);
    float2 r3 = INV ? make_float2(-t3.y, t3.x) : make_float2(t3.y, -t3.x);
    o[0] = cadd(t0, t2);
    o[1] = cadd(t1, r3);
    o[2] = csub(t0, t2);
    o[3] = csub(t1, r3);
}

// First 4 radix-4 passes (s=1,4,16,64) of the 512-FFT over 16 XOR-swizzled
// sequences; 1024 threads: thread owns butterfly f = t&127 of seqs cb, cb+8.
template<bool INV>
__device__ void fft512_4p(float2* buf, const float2* __restrict__ tw, int tid) {
    const int f  = tid & 127;
    const int cb = tid >> 7;          // 0..7 (wave-uniform)
    int s = 1, logs = 0;
#pragma unroll
    for (int pass = 0; pass < 4; ++pass) {
        const int p = f >> logs;
        const int q = f & (s - 1);
        const int wb = q + 4 * s * p;
        const int e = p * s;
        float2 w1 = tw[e], w2 = tw[2 * e], w3 = tw[3 * e];
        if (INV) { w1.y = -w1.y; w2.y = -w2.y; w3.y = -w3.y; }
        float2 u[2][4];
#pragma unroll
        for (int k = 0; k < 2; ++k) {
            const int c = cb + 8 * k;
            float2* sb = buf + c * N1;
#pragma unroll
            for (int j = 0; j < 4; ++j) u[k][j] = sb[(f + 128 * j) ^ c];
        }
        __syncthreads();
#pragma unroll
        for (int k = 0; k < 2; ++k) {
            const int c = cb + 8 * k;
            float2* sb = buf + c * N1;
            float2 o[4];
            bfly4<INV>(u[k], w1, w2, w3, o);
            sb[wb ^ c]           = o[0];
            sb[(wb + s) ^ c]     = o[1];
            sb[(wb + 2 * s) ^ c] = o[2];
            sb[(wb + 3 * s) ^ c] = o[3];
        }
        __syncthreads();
        s <<= 2; logs += 2;
    }
}

// Radix-4 passes [FIRST, FIRST+COUNT) of the 1024-FFT over 4 rows; 1024
// threads: thread owns butterfly f = t&255 of row r = t>>8.
template<bool INV, int FIRST, int COUNT>
__device__ void fft1024_mid(float2* buf, const float2* __restrict__ tw, int tid) {
    const int f = tid & 255;
    const int r = tid >> 8;           // 0..3
    float2* sb = buf + r * N2;
    int s = 1 << (2 * FIRST), logs = 2 * FIRST;
#pragma unroll
    for (int pass = 0; pass < COUNT; ++pass) {
        const int p = f >> logs;
        const int q = f & (s - 1);
        const int wb = q + 4 * s * p;
        const int e = p * s;
        float2 w1 = tw[e], w2 = tw[2 * e], w3 = tw[3 * e];
        if (INV) { w1.y = -w1.y; w2.y = -w2.y; w3.y = -w3.y; }
        float2 u[4];
#pragma unroll
        for (int j = 0; j < 4; ++j) u[j] = sb[f + 256 * j];
        __syncthreads();
        float2 o[4];
        bfly4<INV>(u, w1, w2, w3, o);
        sb[wb]         = o[0];
        sb[wb + s]     = o[1];
        sb[wb + 2 * s] = o[2];
        sb[wb + 3 * s] = o[3];
        __syncthreads();
        s <<= 2; logs += 2;
    }
}

// ---- stage-1 tile helpers (tile t: sig = t>>6, col0 = (t&63)*C1) ----
struct S1Pre { float4 a[2], b[2]; };

__device__ inline void s1_load(const float* __restrict__ x, const float* __restrict__ ir,
                               int t, int tid, S1Pre& p) {
    const int sig  = t >> 6;
    const int col0 = (t & 63) * C1;
#pragma unroll
    for (int it = 0; it < 2; ++it) {
        const int qi = tid + 1024 * it;     // 2048 quads
        const int n1 = qi >> 2;
        const int c4 = (qi & 3) * 4;
        const int n  = n1 * N2 + col0 + c4; // n % 4 == 0
        float4 a = make_float4(0.f, 0.f, 0.f, 0.f);
        float4 b = a;
        if (sig < NSIG) {
            if (n < TT) {
                a = *(const float4*)(x + (size_t)(2 * sig) * TT + n);
                b = *(const float4*)(x + (size_t)(2 * sig + 1) * TT + n);
            }
        } else if (n < IRL) {
            a = *(const float4*)(ir + n);
        }
        p.a[it] = a;
        p.b[it] = b;
    }
}

// Stage 1 (forward), persistent: 512-pt column FFTs for 16 consecutive n2 per
// tile; register prefetch of the next tile overlaps the FFT phases.
__global__ __launch_bounds__(1024) void k_stage1(const float* __restrict__ x,
                                                 const float* __restrict__ ir,
                                                 float2* __restrict__ bufA,
                                                 float2* __restrict__ irA) {
    __shared__ float2 buf[C1 * N1];   // 64 KB
    __shared__ float2 tw[N1];         // 4 KB, W_512^j
    const int tid = threadIdx.x;
    constexpr int NT = (NSIG + 1) * (N2 / C1);   // 1088 tiles

    if (tid < N1) {
        float sn, cs;
        __sincosf(NTWOPI * (float)tid * (1.0f / (float)N1), &sn, &cs);
        tw[tid] = make_float2(cs, sn);
    }

    S1Pre cur, nxt;
    int t = blockIdx.x;
    s1_load(x, ir, t, tid, cur);

    for (; t < NT; t += GRID) {
        // fill LDS from registers
#pragma unroll
        for (int it = 0; it < 2; ++it) {
            const int qi = tid + 1024 * it;
            const int n1 = qi >> 2;
            const int c4 = (qi & 3) * 4;
            buf[(c4 + 0) * N1 + (n1 ^ (c4 + 0))] = make_float2(cur.a[it].x, cur.b[it].x);
            buf[(c4 + 1) * N1 + (n1 ^ (c4 + 1))] = make_float2(cur.a[it].y, cur.b[it].y);
            buf[(c4 + 2) * N1 + (n1 ^ (c4 + 2))] = make_float2(cur.a[it].z, cur.b[it].z);
            buf[(c4 + 3) * N1 + (n1 ^ (c4 + 3))] = make_float2(cur.a[it].w, cur.b[it].w);
        }
        __syncthreads();

        const int tn = t + GRID;
        if (tn < NT) s1_load(x, ir, tn, tid, nxt);   // prefetch; drains during FFT

        fft512_4p<false>(buf, tw, tid);

        // fused: final radix-2 + W_N^{n2*k1} twiddle recurrence + store.
        const int sig  = t >> 6;
        const int col0 = (t & 63) * C1;
        float2* dst = (sig < NSIG) ? (bufA + (size_t)sig * NFFT) : irA;
        const int c  = tid & 15;
        const int fr = tid >> 4;          // 0..63
        const int n2 = col0 + c;
        float2 w0, s64, s256;
        {
            float sn, cs;
            __sincosf(ANG0 * (float)(n2 * fr), &sn, &cs);   w0   = make_float2(cs, sn);
            __sincosf(ANG0 * (float)(n2 * 64), &sn, &cs);   s64  = make_float2(cs, sn);
            __sincosf(ANG0 * (float)(n2 * 256), &sn, &cs);  s256 = make_float2(cs, sn);
        }
#pragma unroll
        for (int it = 0; it < 4; ++it) {
            const int fo = fr + 64 * it;  // 0..255
            float2 a = buf[c * N1 + (fo ^ c)];
            float2 b = buf[c * N1 + ((fo + 256) ^ c)];
            dst[(size_t)fo * N2 + n2]         = cmulf(cadd(a, b), w0);
            dst[(size_t)(fo + 256) * N2 + n2] = cmulf(csub(a, b), cmulf(w0, s256));
            w0 = cmulf(w0, s64);
        }
        __syncthreads();   // WAR: epilogue LDS reads done before next fill
        cur = nxt;
    }
}

// Stage 2, IR path (small, non-persistent): forward 1024-FFT only -> Ht.
__global__ __launch_bounds__(1024) void k_stage2_ir(const float2* __restrict__ src,
                                                    float2* __restrict__ dst) {
    __shared__ float2 buf[R2 * N2];   // 32 KB
    __shared__ float2 tw[N2];         // 8 KB, W_1024^j
    const int r0  = blockIdx.x * R2;
    const int tid = threadIdx.x;

    {
        float sn, cs;
        __sincosf(NTWOPI * (float)tid * (1.0f / (float)N2), &sn, &cs);
        tw[tid] = make_float2(cs, sn);
    }
#pragma unroll
    for (int it = 0; it < 2; ++it) {
        const int qi = tid + 1024 * it;   // 2048 float4
        ((float4*)buf)[qi] = ((const float4*)src)[(size_t)r0 * (N2 / 2) + qi];
    }
    __syncthreads();

    fft1024_mid<false, 0, 4>(buf, tw, tid);

    const int f = tid & 255;
    const int r = tid >> 8;
    float2 u[4], o[4];
#pragma unroll
    for (int j = 0; j < 4; ++j) u[j] = buf[r * N2 + f + 256 * j];
    bfly4_nw<false>(u, o);
#pragma unroll
    for (int j = 0; j < 4; ++j)
        dst[(size_t)(r0 + r) * N2 + f + 256 * j] = o[j];
}

// Stage 2, persistent: fwd 1024-FFT, * Ht, inv 1024-FFT, conj twiddle, store.
// Next-tile src prefetch + current-tile Ht hoist overlap the FFT phases.
__global__ __launch_bounds__(1024) void k_stage2(const float2* __restrict__ src,
                                                 float2* __restrict__ dst,
                                                 const float2* __restrict__ Ht) {
    __shared__ float2 buf[R2 * N2];   // 32 KB
    __shared__ float2 tw[N2];         // 8 KB
    const int tid = threadIdx.x;
    constexpr int NT = NSIG * N1 / R2;   // 2048 tiles

    {
        float sn, cs;
        __sincosf(NTWOPI * (float)tid * (1.0f / (float)N2), &sn, &cs);
        tw[tid] = make_float2(cs, sn);
    }

    const int f = tid & 255;
    const int r = tid >> 8;

    float4 cur[2], nxt[2];
    int t = blockIdx.x;
#pragma unroll
    for (int it = 0; it < 2; ++it)
        cur[it] = ((const float4*)src)[(size_t)t * (R2 * N2 / 2) + tid + 1024 * it];

    for (; t < NT; t += GRID) {
        const int r0 = t * R2;
        const int k1 = (r0 + r) & (N1 - 1);

#pragma unroll
        for (int it = 0; it < 2; ++it)
            ((float4*)buf)[tid + 1024 * it] = cur[it];
        __syncthreads();

        // hoisted Ht loads (consumed after 4 fwd passes) + next-tile prefetch
        float2 h[4];
#pragma unroll
        for (int j = 0; j < 4; ++j) h[j] = Ht[(size_t)k1 * N2 + f + 256 * j];
        const int tn = t + GRID;
        if (tn < NT) {
#pragma unroll
            for (int it = 0; it < 2; ++it)
                nxt[it] = ((const float4*)src)[(size_t)tn * (R2 * N2 / 2) + tid + 1024 * it];
        }

        fft1024_mid<false, 0, 4>(buf, tw, tid);

        {   // fwd p4 (unit tw) -> * Ht -> inv p0 (conj W_1024^{f,2f,3f}), in regs
            float2 u[4];
#pragma unroll
            for (int j = 0; j < 4; ++j) u[j] = buf[r * N2 + f + 256 * j];
            __syncthreads();   // WAR guard
            float2 w1 = tw[f], w2 = tw[2 * f], w3 = tw[3 * f];
            w1.y = -w1.y; w2.y = -w2.y; w3.y = -w3.y;
            float2 o[4], v[4], o2[4];
            bfly4_nw<false>(u, o);
#pragma unroll
            for (int j = 0; j < 4; ++j) v[j] = cmulf(o[j], h[j]);
            bfly4<true>(v, w1, w2, w3, o2);
            float2* sb = buf + r * N2;
#pragma unroll
            for (int j = 0; j < 4; ++j) sb[4 * f + j] = o2[j];   // wb=4f, s=1
            __syncthreads();
        }

        fft1024_mid<true, 1, 3>(buf, tw, tid);   // inv passes s=4,16,64

        // inv final pass (s=256, unit tw) + conj twiddle recurrence + store
        float2 u[4], o[4];
#pragma unroll
        for (int j = 0; j < 4; ++j) u[j] = buf[r * N2 + f + 256 * j];
        bfly4_nw<true>(u, o);
        float2 w, st;
        {
            float sn, cs;
            __sincosf(-ANG0 * (float)(f * k1), &sn, &cs);   w  = make_float2(cs, sn);
            __sincosf(-ANG0 * (float)(256 * k1), &sn, &cs); st = make_float2(cs, sn);
        }
#pragma unroll
        for (int j = 0; j < 4; ++j) {
            dst[(size_t)(r0 + r) * N2 + f + 256 * j] = cmulf(o[j], w);
            w = cmulf(w, st);
        }
        __syncthreads();   // WAR before next fill
        cur[0] = nxt[0]; cur[1] = nxt[1];
    }
}

// ---- stage-3 tile helper (tile t: sig = t>>6, col0 = (t&63)*C1) ----
__device__ inline void s3_load(const float2* __restrict__ bufB, int t, int tid, float4* p) {
    const int sig  = t >> 6;
    const int col0 = (t & 63) * C1;
    const float2* src = bufB + (size_t)sig * NFFT;
    const int cp  = tid & 7;
    const int k1b = tid >> 3;
#pragma unroll
    for (int it = 0; it < 4; ++it) {
        const int k1 = k1b + 128 * it;
        p[it] = *(const float4*)(src + (size_t)k1 * N2 + col0 + 2 * cp);
    }
}

// Stage 3 (inverse), persistent: 512-pt column IFFTs; final radix-2 fused with
// unpack, wet/dry mix, float4 stores; next-tile prefetch overlaps FFT.
__global__ __launch_bounds__(1024) void k_stage3(const float2* __restrict__ bufB,
                                                 const float* __restrict__ x,
                                                 const float* __restrict__ wet_param,
                                                 float* __restrict__ out) {
    __shared__ float2 buf[C1 * N1];   // 64 KB
    __shared__ float2 tw[N1];         // 4 KB
    const int tid = threadIdx.x;
    constexpr int NT = NSIG * (N2 / C1);   // 1024 tiles

    if (tid < N1) {
        float sn, cs;
        __sincosf(NTWOPI * (float)tid * (1.0f / (float)N1), &sn, &cs);
        tw[tid] = make_float2(cs, sn);
    }

    const float wet = 1.0f / (1.0f + expf(-wet_param[0]));
    const float dry = 1.0f - wet;
    const float ws  = wet * (1.0f / (float)NFFT);

    float4 cur[4], nxt[4];
    int t = blockIdx.x;
    s3_load(bufB, t, tid, cur);

    for (; t < NT; t += GRID) {
        {
            const int cp  = tid & 7;
            const int k1b = tid >> 3;
#pragma unroll
            for (int it = 0; it < 4; ++it) {
                const int k1 = k1b + 128 * it;
                const int ca = 2 * cp, cb = 2 * cp + 1;
                buf[ca * N1 + (k1 ^ ca)] = make_float2(cur[it].x, cur[it].y);
                buf[cb * N1 + (k1 ^ cb)] = make_float2(cur[it].z, cur[it].w);
            }
        }
        __syncthreads();

        const int tn = t + GRID;
        if (tn < NT) s3_load(bufB, tn, tid, nxt);   // prefetch; drains during FFT

        fft512_4p<true>(buf, tw, tid);

        const int sig  = t >> 6;
        const int col0 = (t & 63) * C1;
        const float* xa = x + (size_t)(2 * sig) * TT;
        const float* xb = xa + TT;
        float* oa = out + (size_t)(2 * sig) * TT;
        float* ob = oa + TT;

        const int c4 = (tid & 3) * 4;
        const int fo = tid >> 2;          // 0..255
        float2 y0[4], y1[4];
#pragma unroll
        for (int jj = 0; jj < 4; ++jj) {
            const int c = c4 + jj;
            float2 a = buf[c * N1 + (fo ^ c)];
            float2 b = buf[c * N1 + ((fo + 256) ^ c)];
            y0[jj] = cadd(a, b);          // time row fo
            y1[jj] = csub(a, b);          // time row fo+256
        }
#pragma unroll
        for (int h = 0; h < 2; ++h) {
            const int row = fo + 256 * h;
            const int n   = row * N2 + col0 + c4;   // n % 4 == 0
            if (n < TT) {
                const float2* yy = h ? y1 : y0;
                float4 a4 = *(const float4*)(xa + n);
                float4 b4 = *(const float4*)(xb + n);
                float4 ra, rb;
                ra.x = dry * a4.x + ws * yy[0].x;
                ra.y = dry * a4.y + ws * yy[1].x;
                ra.z = dry * a4.z + ws * yy[2].x;
                ra.w = dry * a4.w + ws * yy[3].x;
                rb.x = dry * b4.x + ws * yy[0].y;
                rb.y = dry * b4.y + ws * yy[1].y;
                rb.z = dry * b4.z + ws * yy[2].y;
                rb.w = dry * b4.w + ws * yy[3].y;
                *(float4*)(oa + n) = ra;
                *(float4*)(ob + n) = rb;
            }
        }
        __syncthreads();   // WAR: epilogue LDS reads done before next fill
#pragma unroll
        for (int it = 0; it < 4; ++it) cur[it] = nxt[it];
    }
}

// Correctness fallback if workspace is too small: direct time-domain conv.
__global__ __launch_bounds__(256) void k_direct(const float* __restrict__ x,
                                                const float* __restrict__ ir,
                                                const float* __restrict__ wet_param,
                                                float* __restrict__ out) {
    __shared__ float irs[1024];
    const int b = blockIdx.y;
    const int n = blockIdx.x * 256 + threadIdx.x;
    float acc = 0.0f;
    for (int k0 = 0; k0 < IRL; k0 += 1024) {
        __syncthreads();
        for (int j = threadIdx.x; j < 1024; j += 256) {
            const int k = k0 + j;
            irs[j] = (k < IRL) ? ir[k] : 0.0f;
        }
        __syncthreads();
        if (n < TT) {
            const int kend = min(1024, n - k0 + 1);
            for (int k = 0; k < kend; ++k)
                acc += irs[k] * x[(size_t)b * TT + (n - k0 - k)];
        }
    }
    if (n < TT) {
        const float wet = 1.0f / (1.0f + expf(-wet_param[0]));
        out[(size_t)b * TT + n] = (1.0f - wet) * x[(size_t)b * TT + n] + wet * acc;
    }
}

extern "C" void kernel_launch(void* const* d_in, const int* in_sizes, int n_in,
                              void* d_out, int out_size, void* d_ws, size_t ws_size,
                              hipStream_t stream) {
    (void)in_sizes; (void)n_in; (void)out_size;
    const float* x   = (const float*)d_in[0];
    const float* ir  = (const float*)d_in[1];
    const float* wet = (const float*)d_in[2];
    float* out = (float*)d_out;

    // ws: Ht(NFFT) + bufA(16*NFFT) + bufB(16*NFFT)
    const size_t need = (size_t)(1 + 2 * NSIG) * (size_t)NFFT * sizeof(float2);
    if (ws_size < need) {
        dim3 g((TT + 255) / 256, 32);
        k_direct<<<g, 256, 0, stream>>>(x, ir, wet, out);
        return;
    }

    float2* Ht   = (float2*)d_ws;
    float2* bufA = Ht + NFFT;
    float2* bufB = bufA + (size_t)NSIG * NFFT;
    float2* irA  = bufB;   // reuse bufB start before it is written

    k_stage1<<<dim3(GRID), 1024, 0, stream>>>(x, ir, bufA, irA);
    k_stage2_ir<<<dim3(N1 / R2), 1024, 0, stream>>>(irA, Ht);
    k_stage2<<<dim3(GRID), 1024, 0, stream>>>(bufA, bufB, Ht);
    k_stage3<<<dim3(GRID), 1024, 0, stream>>>(bufB, x, wet, out);
}